// Round 4
// baseline (296.355 us; speedup 1.0000x reference)
//
#include <hip/hip_runtime.h>

// RGCN layer, basis decomposition — CSR-reordered formulation.
//
//   G[n][b][i] = sum_{e: dst[e]==n} (norm_e * w_comp[etype_e][b]) * h[src_e][i]
//   out[n][o]  = relu( sum_b sum_i G[n][b][i] * weight[b][i][o] + bias[o] )
//
// Pipeline: hist(dst) -> single-block scan -> fill(sorted edge records) ->
// aggregate (wave-uniform scalar record loads + 8-deep pipelined h gathers,
// no atomics) -> dense transform GEMM (fused bias+relu).

constexpr int BASES = 4;

// ============================ CSR build ============================

__global__ __launch_bounds__(256) void hist_kernel(const int* __restrict__ dst,
                                                   int* __restrict__ counts, int E) {
    int tid = blockIdx.x * blockDim.x + threadIdx.x;
    int st = gridDim.x * blockDim.x;
    int nq = E >> 2;
    for (int q = tid; q < nq; q += st) {
        int4 d4 = ((const int4*)dst)[q];
        atomicAdd(&counts[d4.x], 1);
        atomicAdd(&counts[d4.y], 1);
        atomicAdd(&counts[d4.z], 1);
        atomicAdd(&counts[d4.w], 1);
    }
    int rem = E - (nq << 2);
    if (tid < rem) atomicAdd(&counts[dst[(nq << 2) + tid]], 1);
}

// single-block exclusive scan over counts -> offsets, cursor; offsets[N] = E
__global__ __launch_bounds__(1024) void scan_kernel(const int* __restrict__ counts,
                                                    int* __restrict__ offsets,
                                                    int* __restrict__ cursor, int N, int E) {
    __shared__ int s[1024];
    const int t = threadIdx.x;
    const int per = (N + 1023) >> 10;
    const int i0 = t * per;
    const int i1 = (i0 + per < N) ? (i0 + per) : N;
    int sum = 0;
    for (int i = i0; i < i1; ++i) sum += counts[i];
    s[t] = sum;
    __syncthreads();
    for (int off = 1; off < 1024; off <<= 1) {
        int x = (t >= off) ? s[t - off] : 0;
        __syncthreads();
        s[t] += x;
        __syncthreads();
    }
    int run = s[t] - sum;                     // exclusive prefix for this chunk
    for (int i = i0; i < i1; ++i) {
        offsets[i] = run;
        cursor[i] = run;
        run += counts[i];
    }
    if (t == 0) offsets[N] = E;
}

// scatter edges into dst-sorted order as packed 16B records {src, etype, norm, 0}
// 4-wide: int4 metadata loads, 4 independent cursor atomics in flight.
__global__ __launch_bounds__(256) void fill_kernel(const int* __restrict__ src,
                                                   const int* __restrict__ dst,
                                                   const int* __restrict__ etype,
                                                   const float* __restrict__ norm,
                                                   int* __restrict__ cursor,
                                                   uint4* __restrict__ packed, int E) {
    int tid = blockIdx.x * blockDim.x + threadIdx.x;
    int st = gridDim.x * blockDim.x;
    int nq = E >> 2;
    for (int q = tid; q < nq; q += st) {
        int4 d4 = ((const int4*)dst)[q];
        int4 s4 = ((const int4*)src)[q];
        int4 t4 = ((const int4*)etype)[q];
        float4 n4 = ((const float4*)norm)[q];
        int p0 = atomicAdd(&cursor[d4.x], 1);
        int p1 = atomicAdd(&cursor[d4.y], 1);
        int p2 = atomicAdd(&cursor[d4.z], 1);
        int p3 = atomicAdd(&cursor[d4.w], 1);
        uint4 r0, r1, r2, r3;
        r0.x = (unsigned)s4.x; r0.y = (unsigned)t4.x; r0.z = __float_as_uint(n4.x); r0.w = 0u;
        r1.x = (unsigned)s4.y; r1.y = (unsigned)t4.y; r1.z = __float_as_uint(n4.y); r1.w = 0u;
        r2.x = (unsigned)s4.z; r2.y = (unsigned)t4.z; r2.z = __float_as_uint(n4.z); r2.w = 0u;
        r3.x = (unsigned)s4.w; r3.y = (unsigned)t4.w; r3.z = __float_as_uint(n4.w); r3.w = 0u;
        packed[p0] = r0;
        packed[p1] = r1;
        packed[p2] = r2;
        packed[p3] = r3;
    }
    int rem = E - (nq << 2);
    if (tid < rem) {
        int i = (nq << 2) + tid;
        int d = dst[i];
        int pos = atomicAdd(&cursor[d], 1);
        uint4 r;
        r.x = (unsigned)src[i];
        r.y = (unsigned)etype[i];
        r.z = __float_as_uint(norm[i]);
        r.w = 0u;
        packed[pos] = r;
    }
}

// ============================ Aggregation ============================
// One wave per node (lane = feature i). Wave index forced uniform via
// readfirstlane so record/coeff/offset loads scalarize to SGPRs (s_load);
// only the h gathers use the vector-memory pipe. 8-deep phase-separated
// groups with sched_barrier fences for real memory-level parallelism.
__global__ __launch_bounds__(256) void agg_kernel(const uint4* __restrict__ packed,
                                                  const int* __restrict__ offsets,
                                                  const float* __restrict__ h,
                                                  const float4* __restrict__ wc4,
                                                  float* __restrict__ G, int N) {
    const int t = threadIdx.x;
    const int lane = t & 63;
    const int wave = __builtin_amdgcn_readfirstlane((blockIdx.x * blockDim.x + t) >> 6);
    const int nw = (gridDim.x * blockDim.x) >> 6;

    for (int n = wave; n < N; n += nw) {
        const int e0 = offsets[n], e1 = offsets[n + 1];
        float g0 = 0.f, g1 = 0.f, g2 = 0.f, g3 = 0.f;
        int e = e0;
        for (; e + 8 <= e1; e += 8) {
            uint4 r[8];
#pragma unroll
            for (int k = 0; k < 8; ++k) r[k] = packed[e + k];
            __builtin_amdgcn_sched_barrier(0);
            float hv[8];
            float4 c[8];
#pragma unroll
            for (int k = 0; k < 8; ++k) {
                hv[k] = h[(size_t)r[k].x * 64 + lane];
                c[k] = wc4[r[k].y];
            }
            __builtin_amdgcn_sched_barrier(0);
#pragma unroll
            for (int k = 0; k < 8; ++k) {
                float a = __uint_as_float(r[k].z) * hv[k];
                g0 = fmaf(c[k].x, a, g0);
                g1 = fmaf(c[k].y, a, g1);
                g2 = fmaf(c[k].z, a, g2);
                g3 = fmaf(c[k].w, a, g3);
            }
        }
        if (e + 4 <= e1) {
            uint4 r[4];
#pragma unroll
            for (int k = 0; k < 4; ++k) r[k] = packed[e + k];
            __builtin_amdgcn_sched_barrier(0);
            float hv[4];
            float4 c[4];
#pragma unroll
            for (int k = 0; k < 4; ++k) {
                hv[k] = h[(size_t)r[k].x * 64 + lane];
                c[k] = wc4[r[k].y];
            }
            __builtin_amdgcn_sched_barrier(0);
#pragma unroll
            for (int k = 0; k < 4; ++k) {
                float a = __uint_as_float(r[k].z) * hv[k];
                g0 = fmaf(c[k].x, a, g0);
                g1 = fmaf(c[k].y, a, g1);
                g2 = fmaf(c[k].z, a, g2);
                g3 = fmaf(c[k].w, a, g3);
            }
            e += 4;
        }
        for (; e < e1; ++e) {
            uint4 rec = packed[e];
            float hv = h[(size_t)rec.x * 64 + lane];
            float4 cc = wc4[rec.y];
            float a = __uint_as_float(rec.z) * hv;
            g0 = fmaf(cc.x, a, g0);
            g1 = fmaf(cc.y, a, g1);
            g2 = fmaf(cc.z, a, g2);
            g3 = fmaf(cc.w, a, g3);
        }
        float* gp = G + (size_t)n * 256;
        gp[lane] = g0;
        gp[64 + lane] = g1;
        gp[128 + lane] = g2;
        gp[192 + lane] = g3;
    }
}

// ============================ Transform GEMM ============================
// out[n][o] = relu(bias[o] + sum_b sum_i G[n][b][i]*weight[b][i][o])
__global__ __launch_bounds__(256) void transform_kernel(const float* __restrict__ G,
                                                        const float* __restrict__ weight,
                                                        const float* __restrict__ bias,
                                                        float* __restrict__ out, int N) {
    __shared__ float sh[16 * 256];
    __shared__ float sp[16 * 256];
    const int t = threadIdx.x;
    const int b = t >> 6, o = t & 63;

    float wcol[64];
#pragma unroll
    for (int i = 0; i < 64; ++i) wcol[i] = weight[b * 4096 + i * 64 + o];
    const float bo = bias[o];

    const int ntiles = (N + 15) / 16;
    for (int tile = blockIdx.x; tile < ntiles; tile += gridDim.x) {
        const int n0 = tile * 16;
#pragma unroll
        for (int p = 0; p < 4; ++p) {                   // load 16x256 floats as float4
            int idx = p * 256 + t;
            int row = idx >> 6, col = idx & 63;
            int n = n0 + row;
            float4 v = (n < N) ? ((const float4*)G)[(size_t)n * 64 + col]
                               : make_float4(0.f, 0.f, 0.f, 0.f);
            ((float4*)sh)[idx] = v;
        }
        __syncthreads();
        for (int r = 0; r < 16; ++r) {
            const float* g = &sh[r * 256 + b * 64];     // wave-uniform -> broadcast
            float acc = 0.f;
#pragma unroll
            for (int i = 0; i < 64; i += 4) {
                float4 gv = *(const float4*)&g[i];
                acc = fmaf(gv.x, wcol[i], acc);
                acc = fmaf(gv.y, wcol[i + 1], acc);
                acc = fmaf(gv.z, wcol[i + 2], acc);
                acc = fmaf(gv.w, wcol[i + 3], acc);
            }
            sp[r * 256 + b * 64 + o] = acc;
        }
        __syncthreads();
#pragma unroll
        for (int p = 0; p < 4; ++p) {                   // reduce 4 basis partials
            int j = p * 256 + t;
            int r = j >> 6, oo = j & 63;
            int n = n0 + r;
            if (n < N) {
                float v = sp[r * 256 + oo] + sp[r * 256 + 64 + oo] +
                          sp[r * 256 + 128 + oo] + sp[r * 256 + 192 + oo] + bo;
                out[(size_t)n * 64 + oo] = v > 0.f ? v : 0.f;
            }
        }
        __syncthreads();
    }
}

// ============================ Fallback path ============================

__global__ __launch_bounds__(256) void hb_kernel(const float* __restrict__ h,
                                                 const float* __restrict__ weight,
                                                 float* __restrict__ Hb, int N) {
    __shared__ float sh[16][64];
    const int t = threadIdx.x;
    const int b = t >> 6;
    const int o = t & 63;
    float wcol[64];
#pragma unroll
    for (int i = 0; i < 64; ++i) wcol[i] = weight[b * 4096 + i * 64 + o];
    for (int node0 = blockIdx.x * 16; node0 < N; node0 += gridDim.x * 16) {
        __syncthreads();
#pragma unroll
        for (int p = 0; p < 4; ++p) {
            int idx = p * 256 + t;
            int r = idx >> 6, c = idx & 63;
            int node = node0 + r;
            sh[r][c] = (node < N) ? h[(size_t)node * 64 + c] : 0.f;
        }
        __syncthreads();
        int rmax = (N - node0 < 16) ? (N - node0) : 16;
        for (int r = 0; r < rmax; ++r) {
            float acc = 0.f;
#pragma unroll
            for (int i = 0; i < 64; ++i) acc += sh[r][i] * wcol[i];
            Hb[(size_t)(node0 + r) * 256 + t] = acc;
        }
    }
}

__global__ __launch_bounds__(256) void edge_kernel(const float* __restrict__ Hb,
                                                   const float* __restrict__ w_comp,
                                                   const float* __restrict__ edge_norm,
                                                   const int* __restrict__ src,
                                                   const int* __restrict__ dst,
                                                   const int* __restrict__ etype,
                                                   float* __restrict__ out, int E) {
    const int lane = threadIdx.x & 63;
    const int gwave = (blockIdx.x * blockDim.x + threadIdx.x) >> 6;
    const int nwaves = (gridDim.x * blockDim.x) >> 6;
    const int chunk = (E + nwaves - 1) / nwaves;
    const int e0 = gwave * chunk;
    const int e1 = (e0 + chunk < E) ? (e0 + chunk) : E;
    for (int e = e0; e < e1; ++e) {
        int s = src[e];
        int d = dst[e];
        int r = etype[e];
        float nm = edge_norm[e];
        const float* hb = Hb + (size_t)s * 256;
        const float* cf = w_comp + r * 4;
        float v = cf[0] * hb[lane] + cf[1] * hb[64 + lane] + cf[2] * hb[128 + lane] +
                  cf[3] * hb[192 + lane];
        atomicAdd(&out[(size_t)d * 64 + lane], v * nm);
    }
}

__global__ __launch_bounds__(256) void bias_relu_kernel(float* __restrict__ out,
                                                        const float* __restrict__ bias,
                                                        int total) {
    int i = blockIdx.x * blockDim.x + threadIdx.x;
    int stride = gridDim.x * blockDim.x;
    for (; i < total; i += stride) {
        float v = out[i] + bias[i & 63];
        out[i] = v > 0.f ? v : 0.f;
    }
}

// ============================ Launch ============================

extern "C" void kernel_launch(void* const* d_in, const int* in_sizes, int n_in,
                              void* d_out, int out_size, void* d_ws, size_t ws_size,
                              hipStream_t stream) {
    const float* h         = (const float*)d_in[0];
    const float* weight    = (const float*)d_in[1];
    const float* w_comp    = (const float*)d_in[2];
    const float* bias      = (const float*)d_in[3];
    const float* edge_norm = (const float*)d_in[4];
    const int*   src       = (const int*)d_in[5];
    const int*   dst       = (const int*)d_in[6];
    const int*   etype     = (const int*)d_in[7];
    float* out = (float*)d_out;

    const int N = in_sizes[0] / 64;
    const int E = in_sizes[4];

    // workspace layout for the CSR path
    size_t gBytes      = (size_t)N * 256 * sizeof(float);   // G
    size_t packedBytes = (size_t)E * 16;                    // sorted edge records
    size_t intsBytes   = (size_t)(N + (N + 1) + N) * sizeof(int);
    size_t need        = gBytes + packedBytes + intsBytes;

    if (ws_size >= need) {
        char* p = (char*)d_ws;
        float* G       = (float*)p;                 p += gBytes;
        uint4* packed  = (uint4*)p;                 p += packedBytes;
        int* counts    = (int*)p;                   p += (size_t)N * sizeof(int);
        int* offsets   = (int*)p;                   p += (size_t)(N + 1) * sizeof(int);
        int* cursor    = (int*)p;

        hipMemsetAsync(counts, 0, (size_t)N * sizeof(int), stream);
        hist_kernel<<<1024, 256, 0, stream>>>(dst, counts, E);
        scan_kernel<<<1, 1024, 0, stream>>>(counts, offsets, cursor, N, E);
        fill_kernel<<<1024, 256, 0, stream>>>(src, dst, etype, edge_norm, cursor, packed, E);
        agg_kernel<<<2048, 256, 0, stream>>>(packed, offsets, h, (const float4*)w_comp, G, N);
        transform_kernel<<<1024, 256, 0, stream>>>(G, weight, bias, out, N);
    } else if (ws_size >= gBytes) {
        float* Hb = (float*)d_ws;
        hipMemsetAsync(d_out, 0, (size_t)N * 64 * sizeof(float), stream);
        hb_kernel<<<1024, 256, 0, stream>>>(h, weight, Hb, N);
        edge_kernel<<<2048, 256, 0, stream>>>(Hb, w_comp, edge_norm, src, dst, etype, out, E);
        bias_relu_kernel<<<2048, 256, 0, stream>>>(out, bias, N * 64);
    }
}

// Round 5
// 198.676 us; speedup vs baseline: 1.4916x; 1.4916x over previous
//
#include <hip/hip_runtime.h>

// RGCN layer, basis decomposition — CSR-reordered formulation.
//
//   G[n][b][i] = sum_{e: dst[e]==n} (norm_e * w_comp[etype_e][b]) * h[src_e][i]
//   out[n][o]  = relu( sum_b sum_i G[n][b][i] * weight[b][i][o] + bias[o] )
//
// Pipeline: hist(dst) -> hierarchical scan (3 small kernels, all-CU parallel)
// -> fill(sorted edge records) -> aggregate (wave-uniform scalar record loads
// + 8-deep pipelined h gathers, no atomics) -> dense transform GEMM.

constexpr int BASES = 4;

// ============================ CSR build ============================

__global__ __launch_bounds__(256) void hist_kernel(const int* __restrict__ dst,
                                                   int* __restrict__ counts, int E) {
    int tid = blockIdx.x * blockDim.x + threadIdx.x;
    int st = gridDim.x * blockDim.x;
    int nq = E >> 2;
    for (int q = tid; q < nq; q += st) {
        int4 d4 = ((const int4*)dst)[q];
        atomicAdd(&counts[d4.x], 1);
        atomicAdd(&counts[d4.y], 1);
        atomicAdd(&counts[d4.z], 1);
        atomicAdd(&counts[d4.w], 1);
    }
    int rem = E - (nq << 2);
    if (tid < rem) atomicAdd(&counts[dst[(nq << 2) + tid]], 1);
}

// per-block sums of 256 counts
__global__ __launch_bounds__(256) void scan1_kernel(const int* __restrict__ counts,
                                                    int* __restrict__ bsum, int N) {
    __shared__ int s[256];
    int t = threadIdx.x;
    int i = blockIdx.x * 256 + t;
    s[t] = (i < N) ? counts[i] : 0;
    __syncthreads();
    for (int off = 128; off > 0; off >>= 1) {
        if (t < off) s[t] += s[t + off];
        __syncthreads();
    }
    if (t == 0) bsum[blockIdx.x] = s[0];
}

// exclusive scan of block sums (nb <= 256); also writes offsets[N] = E
__global__ __launch_bounds__(256) void scan2_kernel(int* __restrict__ bsum, int nb,
                                                    int* __restrict__ offsets, int N, int E) {
    __shared__ int s[256];
    int t = threadIdx.x;
    int v = (t < nb) ? bsum[t] : 0;
    s[t] = v;
    __syncthreads();
    for (int off = 1; off < 256; off <<= 1) {
        int x = (t >= off) ? s[t - off] : 0;
        __syncthreads();
        s[t] += x;
        __syncthreads();
    }
    if (t < nb) bsum[t] = s[t] - v;   // exclusive
    if (t == 0) offsets[N] = E;
}

// per-block exclusive scan + block offset -> offsets & cursor copy
__global__ __launch_bounds__(256) void scan3_kernel(const int* __restrict__ counts,
                                                    const int* __restrict__ bsum,
                                                    int* __restrict__ offsets,
                                                    int* __restrict__ cursor, int N) {
    __shared__ int s[256];
    int t = threadIdx.x;
    int i = blockIdx.x * 256 + t;
    int v = (i < N) ? counts[i] : 0;
    s[t] = v;
    __syncthreads();
    for (int off = 1; off < 256; off <<= 1) {
        int x = (t >= off) ? s[t - off] : 0;
        __syncthreads();
        s[t] += x;
        __syncthreads();
    }
    if (i < N) {
        int ex = s[t] - v + bsum[blockIdx.x];
        offsets[i] = ex;
        cursor[i] = ex;
    }
}

// scatter edges into dst-sorted order as packed 16B records {src, etype, norm, 0}
// 4-wide: int4 metadata loads, 4 independent cursor atomics in flight.
__global__ __launch_bounds__(256) void fill_kernel(const int* __restrict__ src,
                                                   const int* __restrict__ dst,
                                                   const int* __restrict__ etype,
                                                   const float* __restrict__ norm,
                                                   int* __restrict__ cursor,
                                                   uint4* __restrict__ packed, int E) {
    int tid = blockIdx.x * blockDim.x + threadIdx.x;
    int st = gridDim.x * blockDim.x;
    int nq = E >> 2;
    for (int q = tid; q < nq; q += st) {
        int4 d4 = ((const int4*)dst)[q];
        int4 s4 = ((const int4*)src)[q];
        int4 t4 = ((const int4*)etype)[q];
        float4 n4 = ((const float4*)norm)[q];
        int p0 = atomicAdd(&cursor[d4.x], 1);
        int p1 = atomicAdd(&cursor[d4.y], 1);
        int p2 = atomicAdd(&cursor[d4.z], 1);
        int p3 = atomicAdd(&cursor[d4.w], 1);
        uint4 r0, r1, r2, r3;
        r0.x = (unsigned)s4.x; r0.y = (unsigned)t4.x; r0.z = __float_as_uint(n4.x); r0.w = 0u;
        r1.x = (unsigned)s4.y; r1.y = (unsigned)t4.y; r1.z = __float_as_uint(n4.y); r1.w = 0u;
        r2.x = (unsigned)s4.z; r2.y = (unsigned)t4.z; r2.z = __float_as_uint(n4.z); r2.w = 0u;
        r3.x = (unsigned)s4.w; r3.y = (unsigned)t4.w; r3.z = __float_as_uint(n4.w); r3.w = 0u;
        packed[p0] = r0;
        packed[p1] = r1;
        packed[p2] = r2;
        packed[p3] = r3;
    }
    int rem = E - (nq << 2);
    if (tid < rem) {
        int i = (nq << 2) + tid;
        int d = dst[i];
        int pos = atomicAdd(&cursor[d], 1);
        uint4 r;
        r.x = (unsigned)src[i];
        r.y = (unsigned)etype[i];
        r.z = __float_as_uint(norm[i]);
        r.w = 0u;
        packed[pos] = r;
    }
}

// ============================ Aggregation ============================
// One wave per node (lane = feature i). Wave index forced uniform via
// readfirstlane so record/coeff/offset loads scalarize to SGPRs (s_load);
// only the h gathers use the vector-memory pipe. 8-deep phase-separated
// groups with sched_barrier fences for real memory-level parallelism.
__global__ __launch_bounds__(256) void agg_kernel(const uint4* __restrict__ packed,
                                                  const int* __restrict__ offsets,
                                                  const float* __restrict__ h,
                                                  const float4* __restrict__ wc4,
                                                  float* __restrict__ G, int N) {
    const int t = threadIdx.x;
    const int lane = t & 63;
    const int wave = __builtin_amdgcn_readfirstlane((blockIdx.x * blockDim.x + t) >> 6);
    const int nw = (gridDim.x * blockDim.x) >> 6;

    for (int n = wave; n < N; n += nw) {
        const int e0 = offsets[n], e1 = offsets[n + 1];
        float g0 = 0.f, g1 = 0.f, g2 = 0.f, g3 = 0.f;
        int e = e0;
        for (; e + 8 <= e1; e += 8) {
            uint4 r[8];
#pragma unroll
            for (int k = 0; k < 8; ++k) r[k] = packed[e + k];
            __builtin_amdgcn_sched_barrier(0);
            float hv[8];
            float4 c[8];
#pragma unroll
            for (int k = 0; k < 8; ++k) {
                hv[k] = h[(size_t)r[k].x * 64 + lane];
                c[k] = wc4[r[k].y];
            }
            __builtin_amdgcn_sched_barrier(0);
#pragma unroll
            for (int k = 0; k < 8; ++k) {
                float a = __uint_as_float(r[k].z) * hv[k];
                g0 = fmaf(c[k].x, a, g0);
                g1 = fmaf(c[k].y, a, g1);
                g2 = fmaf(c[k].z, a, g2);
                g3 = fmaf(c[k].w, a, g3);
            }
        }
        if (e + 4 <= e1) {
            uint4 r[4];
#pragma unroll
            for (int k = 0; k < 4; ++k) r[k] = packed[e + k];
            __builtin_amdgcn_sched_barrier(0);
            float hv[4];
            float4 c[4];
#pragma unroll
            for (int k = 0; k < 4; ++k) {
                hv[k] = h[(size_t)r[k].x * 64 + lane];
                c[k] = wc4[r[k].y];
            }
            __builtin_amdgcn_sched_barrier(0);
#pragma unroll
            for (int k = 0; k < 4; ++k) {
                float a = __uint_as_float(r[k].z) * hv[k];
                g0 = fmaf(c[k].x, a, g0);
                g1 = fmaf(c[k].y, a, g1);
                g2 = fmaf(c[k].z, a, g2);
                g3 = fmaf(c[k].w, a, g3);
            }
            e += 4;
        }
        for (; e < e1; ++e) {
            uint4 rec = packed[e];
            float hv = h[(size_t)rec.x * 64 + lane];
            float4 cc = wc4[rec.y];
            float a = __uint_as_float(rec.z) * hv;
            g0 = fmaf(cc.x, a, g0);
            g1 = fmaf(cc.y, a, g1);
            g2 = fmaf(cc.z, a, g2);
            g3 = fmaf(cc.w, a, g3);
        }
        float* gp = G + (size_t)n * 256;
        gp[lane] = g0;
        gp[64 + lane] = g1;
        gp[128 + lane] = g2;
        gp[192 + lane] = g3;
    }
}

// ============================ Transform GEMM ============================
// out[n][o] = relu(bias[o] + sum_b sum_i G[n][b][i]*weight[b][i][o])
__global__ __launch_bounds__(256) void transform_kernel(const float* __restrict__ G,
                                                        const float* __restrict__ weight,
                                                        const float* __restrict__ bias,
                                                        float* __restrict__ out, int N) {
    __shared__ float sh[16 * 256];
    __shared__ float sp[16 * 256];
    const int t = threadIdx.x;
    const int b = t >> 6, o = t & 63;

    float wcol[64];
#pragma unroll
    for (int i = 0; i < 64; ++i) wcol[i] = weight[b * 4096 + i * 64 + o];
    const float bo = bias[o];

    const int ntiles = (N + 15) / 16;
    for (int tile = blockIdx.x; tile < ntiles; tile += gridDim.x) {
        const int n0 = tile * 16;
#pragma unroll
        for (int p = 0; p < 4; ++p) {                   // load 16x256 floats as float4
            int idx = p * 256 + t;
            int row = idx >> 6, col = idx & 63;
            int n = n0 + row;
            float4 v = (n < N) ? ((const float4*)G)[(size_t)n * 64 + col]
                               : make_float4(0.f, 0.f, 0.f, 0.f);
            ((float4*)sh)[idx] = v;
        }
        __syncthreads();
        for (int r = 0; r < 16; ++r) {
            const float* g = &sh[r * 256 + b * 64];     // wave-uniform -> broadcast
            float acc = 0.f;
#pragma unroll
            for (int i = 0; i < 64; i += 4) {
                float4 gv = *(const float4*)&g[i];
                acc = fmaf(gv.x, wcol[i], acc);
                acc = fmaf(gv.y, wcol[i + 1], acc);
                acc = fmaf(gv.z, wcol[i + 2], acc);
                acc = fmaf(gv.w, wcol[i + 3], acc);
            }
            sp[r * 256 + b * 64 + o] = acc;
        }
        __syncthreads();
#pragma unroll
        for (int p = 0; p < 4; ++p) {                   // reduce 4 basis partials
            int j = p * 256 + t;
            int r = j >> 6, oo = j & 63;
            int n = n0 + r;
            if (n < N) {
                float v = sp[r * 256 + oo] + sp[r * 256 + 64 + oo] +
                          sp[r * 256 + 128 + oo] + sp[r * 256 + 192 + oo] + bo;
                out[(size_t)n * 64 + oo] = v > 0.f ? v : 0.f;
            }
        }
        __syncthreads();
    }
}

// ============================ Fallback path ============================

__global__ __launch_bounds__(256) void hb_kernel(const float* __restrict__ h,
                                                 const float* __restrict__ weight,
                                                 float* __restrict__ Hb, int N) {
    __shared__ float sh[16][64];
    const int t = threadIdx.x;
    const int b = t >> 6;
    const int o = t & 63;
    float wcol[64];
#pragma unroll
    for (int i = 0; i < 64; ++i) wcol[i] = weight[b * 4096 + i * 64 + o];
    for (int node0 = blockIdx.x * 16; node0 < N; node0 += gridDim.x * 16) {
        __syncthreads();
#pragma unroll
        for (int p = 0; p < 4; ++p) {
            int idx = p * 256 + t;
            int r = idx >> 6, c = idx & 63;
            int node = node0 + r;
            sh[r][c] = (node < N) ? h[(size_t)node * 64 + c] : 0.f;
        }
        __syncthreads();
        int rmax = (N - node0 < 16) ? (N - node0) : 16;
        for (int r = 0; r < rmax; ++r) {
            float acc = 0.f;
#pragma unroll
            for (int i = 0; i < 64; ++i) acc += sh[r][i] * wcol[i];
            Hb[(size_t)(node0 + r) * 256 + t] = acc;
        }
    }
}

__global__ __launch_bounds__(256) void edge_kernel(const float* __restrict__ Hb,
                                                   const float* __restrict__ w_comp,
                                                   const float* __restrict__ edge_norm,
                                                   const int* __restrict__ src,
                                                   const int* __restrict__ dst,
                                                   const int* __restrict__ etype,
                                                   float* __restrict__ out, int E) {
    const int lane = threadIdx.x & 63;
    const int gwave = (blockIdx.x * blockDim.x + threadIdx.x) >> 6;
    const int nwaves = (gridDim.x * blockDim.x) >> 6;
    const int chunk = (E + nwaves - 1) / nwaves;
    const int e0 = gwave * chunk;
    const int e1 = (e0 + chunk < E) ? (e0 + chunk) : E;
    for (int e = e0; e < e1; ++e) {
        int s = src[e];
        int d = dst[e];
        int r = etype[e];
        float nm = edge_norm[e];
        const float* hb = Hb + (size_t)s * 256;
        const float* cf = w_comp + r * 4;
        float v = cf[0] * hb[lane] + cf[1] * hb[64 + lane] + cf[2] * hb[128 + lane] +
                  cf[3] * hb[192 + lane];
        atomicAdd(&out[(size_t)d * 64 + lane], v * nm);
    }
}

__global__ __launch_bounds__(256) void bias_relu_kernel(float* __restrict__ out,
                                                        const float* __restrict__ bias,
                                                        int total) {
    int i = blockIdx.x * blockDim.x + threadIdx.x;
    int stride = gridDim.x * blockDim.x;
    for (; i < total; i += stride) {
        float v = out[i] + bias[i & 63];
        out[i] = v > 0.f ? v : 0.f;
    }
}

// ============================ Launch ============================

extern "C" void kernel_launch(void* const* d_in, const int* in_sizes, int n_in,
                              void* d_out, int out_size, void* d_ws, size_t ws_size,
                              hipStream_t stream) {
    const float* h         = (const float*)d_in[0];
    const float* weight    = (const float*)d_in[1];
    const float* w_comp    = (const float*)d_in[2];
    const float* bias      = (const float*)d_in[3];
    const float* edge_norm = (const float*)d_in[4];
    const int*   src       = (const int*)d_in[5];
    const int*   dst       = (const int*)d_in[6];
    const int*   etype     = (const int*)d_in[7];
    float* out = (float*)d_out;

    const int N = in_sizes[0] / 64;
    const int E = in_sizes[4];
    const int nb = (N + 255) / 256;

    // workspace layout for the CSR path
    size_t gBytes      = (size_t)N * 256 * sizeof(float);   // G
    size_t packedBytes = (size_t)E * 16;                    // sorted edge records
    size_t intsBytes   = (size_t)(N + (N + 1) + N + nb) * sizeof(int);
    size_t need        = gBytes + packedBytes + intsBytes;

    if (ws_size >= need && nb <= 256) {
        char* p = (char*)d_ws;
        float* G       = (float*)p;                 p += gBytes;
        uint4* packed  = (uint4*)p;                 p += packedBytes;
        int* counts    = (int*)p;                   p += (size_t)N * sizeof(int);
        int* offsets   = (int*)p;                   p += (size_t)(N + 1) * sizeof(int);
        int* cursor    = (int*)p;                   p += (size_t)N * sizeof(int);
        int* bsum      = (int*)p;

        hipMemsetAsync(counts, 0, (size_t)N * sizeof(int), stream);
        hist_kernel<<<1024, 256, 0, stream>>>(dst, counts, E);
        scan1_kernel<<<nb, 256, 0, stream>>>(counts, bsum, N);
        scan2_kernel<<<1, 256, 0, stream>>>(bsum, nb, offsets, N, E);
        scan3_kernel<<<nb, 256, 0, stream>>>(counts, bsum, offsets, cursor, N);
        fill_kernel<<<1024, 256, 0, stream>>>(src, dst, etype, edge_norm, cursor, packed, E);
        agg_kernel<<<2048, 256, 0, stream>>>(packed, offsets, h, (const float4*)w_comp, G, N);
        transform_kernel<<<1024, 256, 0, stream>>>(G, weight, bias, out, N);
    } else if (ws_size >= gBytes) {
        float* Hb = (float*)d_ws;
        hipMemsetAsync(d_out, 0, (size_t)N * 64 * sizeof(float), stream);
        hb_kernel<<<1024, 256, 0, stream>>>(h, weight, Hb, N);
        edge_kernel<<<2048, 256, 0, stream>>>(Hb, w_comp, edge_norm, src, dst, etype, out, E);
        bias_relu_kernel<<<2048, 256, 0, stream>>>(out, bias, N * 64);
    }
}

// Round 6
// 195.412 us; speedup vs baseline: 1.5166x; 1.0167x over previous
//
#include <hip/hip_runtime.h>

// RGCN layer, basis decomposition — CSR-reordered formulation.
//
//   G[n][b][i] = sum_{e: dst[e]==n} (norm_e * w_comp[etype_e][b]) * h[src_e][i]
//   out[n][o]  = relu( sum_b sum_i G[n][b][i] * weight[b][i][o] + bias[o] )
//
// Pipeline: hist(dst) -> hierarchical scan -> fill(sorted edge records) ->
// aggregate (no atomics) -> dense transform GEMM (fused bias+relu).
//
// Atomic traffic (hist counts, fill cursors) is partitioned by block-group
// g = blockIdx.x & 7 (tracks the XCD round-robin) with [g][N] layouts, so
// each atomic cacheline is touched by one XCD only — no cross-XCD ownership
// ping-pong. Node n's edge segment = 8 contiguous sub-segments [n][g=0..7].
// Correctness is independent of the block->XCD mapping; only locality is.

constexpr int NG = 8;   // atomic partition groups

// ============================ CSR build ============================

__global__ __launch_bounds__(256) void hist_kernel(const int* __restrict__ dst,
                                                   int* __restrict__ counts, int N, int E) {
    int* gc = counts + (size_t)(blockIdx.x & (NG - 1)) * N;
    int tid = blockIdx.x * blockDim.x + threadIdx.x;
    int st = gridDim.x * blockDim.x;
    int nq = E >> 2;
    for (int q = tid; q < nq; q += st) {
        int4 d4 = ((const int4*)dst)[q];
        atomicAdd(&gc[d4.x], 1);
        atomicAdd(&gc[d4.y], 1);
        atomicAdd(&gc[d4.z], 1);
        atomicAdd(&gc[d4.w], 1);
    }
    int rem = E - (nq << 2);
    if (tid < rem) atomicAdd(&gc[dst[(nq << 2) + tid]], 1);
}

// per-block sums: block handles 256 nodes x 8 groups (2048 segments)
__global__ __launch_bounds__(256) void scan1_kernel(const int* __restrict__ counts,
                                                    int* __restrict__ bsum, int N) {
    __shared__ int s[256];
    int t = threadIdx.x;
    int n = blockIdx.x * 256 + t;
    int sum = 0;
    if (n < N) {
#pragma unroll
        for (int g = 0; g < NG; ++g) sum += counts[(size_t)g * N + n];
    }
    s[t] = sum;
    __syncthreads();
    for (int off = 128; off > 0; off >>= 1) {
        if (t < off) s[t] += s[t + off];
        __syncthreads();
    }
    if (t == 0) bsum[blockIdx.x] = s[0];
}

// exclusive scan of block sums (nb <= 256)
__global__ __launch_bounds__(256) void scan2_kernel(int* __restrict__ bsum, int nb) {
    __shared__ int s[256];
    int t = threadIdx.x;
    int v = (t < nb) ? bsum[t] : 0;
    s[t] = v;
    __syncthreads();
    for (int off = 1; off < 256; off <<= 1) {
        int x = (t >= off) ? s[t - off] : 0;
        __syncthreads();
        s[t] += x;
        __syncthreads();
    }
    if (t < nb) bsum[t] = s[t] - v;   // exclusive
}

// per-node 8-group exclusive scan + block offset -> offsets8[n*8+g], cursor[g][n]
__global__ __launch_bounds__(256) void scan3_kernel(const int* __restrict__ counts,
                                                    const int* __restrict__ bsum,
                                                    int* __restrict__ offsets8,
                                                    int* __restrict__ cursor, int N, int E) {
    __shared__ int s[256];
    int t = threadIdx.x;
    int n = blockIdx.x * 256 + t;
    int c[NG];
    int sum = 0;
    if (n < N) {
#pragma unroll
        for (int g = 0; g < NG; ++g) {
            c[g] = counts[(size_t)g * N + n];
            sum += c[g];
        }
    }
    s[t] = sum;
    __syncthreads();
    for (int off = 1; off < 256; off <<= 1) {
        int x = (t >= off) ? s[t - off] : 0;
        __syncthreads();
        s[t] += x;
        __syncthreads();
    }
    if (n < N) {
        int run = s[t] - sum + bsum[blockIdx.x];
#pragma unroll
        for (int g = 0; g < NG; ++g) {
            offsets8[(size_t)n * NG + g] = run;
            cursor[(size_t)g * N + n] = run;
            run += c[g];
        }
    }
    if (blockIdx.x == 0 && t == 0) offsets8[(size_t)N * NG] = E;
}

// scatter edges into dst-sorted order as packed 16B records {src, etype, norm, 0}
// cursor partitioned by block-group -> XCD-local atomic lines.
__global__ __launch_bounds__(256) void fill_kernel(const int* __restrict__ src,
                                                   const int* __restrict__ dst,
                                                   const int* __restrict__ etype,
                                                   const float* __restrict__ norm,
                                                   int* __restrict__ cursor,
                                                   uint4* __restrict__ packed, int N, int E) {
    int* gcur = cursor + (size_t)(blockIdx.x & (NG - 1)) * N;
    int tid = blockIdx.x * blockDim.x + threadIdx.x;
    int st = gridDim.x * blockDim.x;
    int nq = E >> 2;
    for (int q = tid; q < nq; q += st) {
        int4 d4 = ((const int4*)dst)[q];
        int4 s4 = ((const int4*)src)[q];
        int4 t4 = ((const int4*)etype)[q];
        float4 n4 = ((const float4*)norm)[q];
        int p0 = atomicAdd(&gcur[d4.x], 1);
        int p1 = atomicAdd(&gcur[d4.y], 1);
        int p2 = atomicAdd(&gcur[d4.z], 1);
        int p3 = atomicAdd(&gcur[d4.w], 1);
        uint4 r0, r1, r2, r3;
        r0.x = (unsigned)s4.x; r0.y = (unsigned)t4.x; r0.z = __float_as_uint(n4.x); r0.w = 0u;
        r1.x = (unsigned)s4.y; r1.y = (unsigned)t4.y; r1.z = __float_as_uint(n4.y); r1.w = 0u;
        r2.x = (unsigned)s4.z; r2.y = (unsigned)t4.z; r2.z = __float_as_uint(n4.z); r2.w = 0u;
        r3.x = (unsigned)s4.w; r3.y = (unsigned)t4.w; r3.z = __float_as_uint(n4.w); r3.w = 0u;
        packed[p0] = r0;
        packed[p1] = r1;
        packed[p2] = r2;
        packed[p3] = r3;
    }
    int rem = E - (nq << 2);
    if (tid < rem) {
        int i = (nq << 2) + tid;
        int d = dst[i];
        int pos = atomicAdd(&gcur[d], 1);
        uint4 r;
        r.x = (unsigned)src[i];
        r.y = (unsigned)etype[i];
        r.z = __float_as_uint(norm[i]);
        r.w = 0u;
        packed[pos] = r;
    }
}

// ============================ Aggregation ============================
// One wave per node (lane = feature i). Wave index forced uniform via
// readfirstlane so record/coeff loads scalarize; 8-deep phase-separated
// load groups with sched_barrier fences for memory-level parallelism.
__global__ __launch_bounds__(256) void agg_kernel(const uint4* __restrict__ packed,
                                                  const int* __restrict__ offsets8,
                                                  const float* __restrict__ h,
                                                  const float4* __restrict__ wc4,
                                                  float* __restrict__ G, int N) {
    const int t = threadIdx.x;
    const int lane = t & 63;
    const int wave = __builtin_amdgcn_readfirstlane((blockIdx.x * blockDim.x + t) >> 6);
    const int nw = (gridDim.x * blockDim.x) >> 6;

    for (int n = wave; n < N; n += nw) {
        const int e0 = offsets8[(size_t)n * NG];
        const int e1 = offsets8[(size_t)(n + 1) * NG];
        float g0 = 0.f, g1 = 0.f, g2 = 0.f, g3 = 0.f;
        int e = e0;
        for (; e + 8 <= e1; e += 8) {
            uint4 r[8];
#pragma unroll
            for (int k = 0; k < 8; ++k) r[k] = packed[e + k];
            __builtin_amdgcn_sched_barrier(0);
            float hv[8];
            float4 c[8];
#pragma unroll
            for (int k = 0; k < 8; ++k) {
                hv[k] = h[(size_t)r[k].x * 64 + lane];
                c[k] = wc4[r[k].y];
            }
            __builtin_amdgcn_sched_barrier(0);
#pragma unroll
            for (int k = 0; k < 8; ++k) {
                float a = __uint_as_float(r[k].z) * hv[k];
                g0 = fmaf(c[k].x, a, g0);
                g1 = fmaf(c[k].y, a, g1);
                g2 = fmaf(c[k].z, a, g2);
                g3 = fmaf(c[k].w, a, g3);
            }
        }
        if (e + 4 <= e1) {
            uint4 r[4];
#pragma unroll
            for (int k = 0; k < 4; ++k) r[k] = packed[e + k];
            __builtin_amdgcn_sched_barrier(0);
            float hv[4];
            float4 c[4];
#pragma unroll
            for (int k = 0; k < 4; ++k) {
                hv[k] = h[(size_t)r[k].x * 64 + lane];
                c[k] = wc4[r[k].y];
            }
            __builtin_amdgcn_sched_barrier(0);
#pragma unroll
            for (int k = 0; k < 4; ++k) {
                float a = __uint_as_float(r[k].z) * hv[k];
                g0 = fmaf(c[k].x, a, g0);
                g1 = fmaf(c[k].y, a, g1);
                g2 = fmaf(c[k].z, a, g2);
                g3 = fmaf(c[k].w, a, g3);
            }
            e += 4;
        }
        for (; e < e1; ++e) {
            uint4 rec = packed[e];
            float hv = h[(size_t)rec.x * 64 + lane];
            float4 cc = wc4[rec.y];
            float a = __uint_as_float(rec.z) * hv;
            g0 = fmaf(cc.x, a, g0);
            g1 = fmaf(cc.y, a, g1);
            g2 = fmaf(cc.z, a, g2);
            g3 = fmaf(cc.w, a, g3);
        }
        float* gp = G + (size_t)n * 256;
        gp[lane] = g0;
        gp[64 + lane] = g1;
        gp[128 + lane] = g2;
        gp[192 + lane] = g3;
    }
}

// ============================ Transform GEMM ============================
// out[n][o] = relu(bias[o] + sum_b sum_i G[n][b][i]*weight[b][i][o])
__global__ __launch_bounds__(256) void transform_kernel(const float* __restrict__ G,
                                                        const float* __restrict__ weight,
                                                        const float* __restrict__ bias,
                                                        float* __restrict__ out, int N) {
    __shared__ float sh[16 * 256];
    __shared__ float sp[16 * 256];
    const int t = threadIdx.x;
    const int b = t >> 6, o = t & 63;

    float wcol[64];
#pragma unroll
    for (int i = 0; i < 64; ++i) wcol[i] = weight[b * 4096 + i * 64 + o];
    const float bo = bias[o];

    const int ntiles = (N + 15) / 16;
    for (int tile = blockIdx.x; tile < ntiles; tile += gridDim.x) {
        const int n0 = tile * 16;
#pragma unroll
        for (int p = 0; p < 4; ++p) {                   // load 16x256 floats as float4
            int idx = p * 256 + t;
            int row = idx >> 6, col = idx & 63;
            int n = n0 + row;
            float4 v = (n < N) ? ((const float4*)G)[(size_t)n * 64 + col]
                               : make_float4(0.f, 0.f, 0.f, 0.f);
            ((float4*)sh)[idx] = v;
        }
        __syncthreads();
        for (int r = 0; r < 16; ++r) {
            const float* g = &sh[r * 256 + b * 64];     // wave-uniform -> broadcast
            float acc = 0.f;
#pragma unroll
            for (int i = 0; i < 64; i += 4) {
                float4 gv = *(const float4*)&g[i];
                acc = fmaf(gv.x, wcol[i], acc);
                acc = fmaf(gv.y, wcol[i + 1], acc);
                acc = fmaf(gv.z, wcol[i + 2], acc);
                acc = fmaf(gv.w, wcol[i + 3], acc);
            }
            sp[r * 256 + b * 64 + o] = acc;
        }
        __syncthreads();
#pragma unroll
        for (int p = 0; p < 4; ++p) {                   // reduce 4 basis partials
            int j = p * 256 + t;
            int r = j >> 6, oo = j & 63;
            int n = n0 + r;
            if (n < N) {
                float v = sp[r * 256 + oo] + sp[r * 256 + 64 + oo] +
                          sp[r * 256 + 128 + oo] + sp[r * 256 + 192 + oo] + bo;
                out[(size_t)n * 64 + oo] = v > 0.f ? v : 0.f;
            }
        }
        __syncthreads();
    }
}

// ============================ Fallback path ============================

__global__ __launch_bounds__(256) void hb_kernel(const float* __restrict__ h,
                                                 const float* __restrict__ weight,
                                                 float* __restrict__ Hb, int N) {
    __shared__ float sh[16][64];
    const int t = threadIdx.x;
    const int b = t >> 6;
    const int o = t & 63;
    float wcol[64];
#pragma unroll
    for (int i = 0; i < 64; ++i) wcol[i] = weight[b * 4096 + i * 64 + o];
    for (int node0 = blockIdx.x * 16; node0 < N; node0 += gridDim.x * 16) {
        __syncthreads();
#pragma unroll
        for (int p = 0; p < 4; ++p) {
            int idx = p * 256 + t;
            int r = idx >> 6, c = idx & 63;
            int node = node0 + r;
            sh[r][c] = (node < N) ? h[(size_t)node * 64 + c] : 0.f;
        }
        __syncthreads();
        int rmax = (N - node0 < 16) ? (N - node0) : 16;
        for (int r = 0; r < rmax; ++r) {
            float acc = 0.f;
#pragma unroll
            for (int i = 0; i < 64; ++i) acc += sh[r][i] * wcol[i];
            Hb[(size_t)(node0 + r) * 256 + t] = acc;
        }
    }
}

__global__ __launch_bounds__(256) void edge_kernel(const float* __restrict__ Hb,
                                                   const float* __restrict__ w_comp,
                                                   const float* __restrict__ edge_norm,
                                                   const int* __restrict__ src,
                                                   const int* __restrict__ dst,
                                                   const int* __restrict__ etype,
                                                   float* __restrict__ out, int E) {
    const int lane = threadIdx.x & 63;
    const int gwave = (blockIdx.x * blockDim.x + threadIdx.x) >> 6;
    const int nwaves = (gridDim.x * blockDim.x) >> 6;
    const int chunk = (E + nwaves - 1) / nwaves;
    const int e0 = gwave * chunk;
    const int e1 = (e0 + chunk < E) ? (e0 + chunk) : E;
    for (int e = e0; e < e1; ++e) {
        int s = src[e];
        int d = dst[e];
        int r = etype[e];
        float nm = edge_norm[e];
        const float* hb = Hb + (size_t)s * 256;
        const float* cf = w_comp + r * 4;
        float v = cf[0] * hb[lane] + cf[1] * hb[64 + lane] + cf[2] * hb[128 + lane] +
                  cf[3] * hb[192 + lane];
        atomicAdd(&out[(size_t)d * 64 + lane], v * nm);
    }
}

__global__ __launch_bounds__(256) void bias_relu_kernel(float* __restrict__ out,
                                                        const float* __restrict__ bias,
                                                        int total) {
    int i = blockIdx.x * blockDim.x + threadIdx.x;
    int stride = gridDim.x * blockDim.x;
    for (; i < total; i += stride) {
        float v = out[i] + bias[i & 63];
        out[i] = v > 0.f ? v : 0.f;
    }
}

// ============================ Launch ============================

extern "C" void kernel_launch(void* const* d_in, const int* in_sizes, int n_in,
                              void* d_out, int out_size, void* d_ws, size_t ws_size,
                              hipStream_t stream) {
    const float* h         = (const float*)d_in[0];
    const float* weight    = (const float*)d_in[1];
    const float* w_comp    = (const float*)d_in[2];
    const float* bias      = (const float*)d_in[3];
    const float* edge_norm = (const float*)d_in[4];
    const int*   src       = (const int*)d_in[5];
    const int*   dst       = (const int*)d_in[6];
    const int*   etype     = (const int*)d_in[7];
    float* out = (float*)d_out;

    const int N = in_sizes[0] / 64;
    const int E = in_sizes[4];
    const int nb = (N + 255) / 256;

    // workspace layout for the CSR path
    size_t gBytes      = (size_t)N * 256 * sizeof(float);       // G
    size_t packedBytes = (size_t)E * 16;                        // sorted edge records
    size_t cntBytes    = (size_t)NG * N * sizeof(int);          // counts (x NG)
    size_t offBytes    = ((size_t)N * NG + 8) * sizeof(int);    // offsets8
    size_t curBytes    = (size_t)NG * N * sizeof(int);          // cursor (x NG)
    size_t need        = gBytes + packedBytes + cntBytes + offBytes + curBytes + 1024;

    if (ws_size >= need && nb <= 256) {
        char* p = (char*)d_ws;
        float* G        = (float*)p;                p += gBytes;
        uint4* packed   = (uint4*)p;                p += packedBytes;
        int* counts     = (int*)p;                  p += cntBytes;
        int* offsets8   = (int*)p;                  p += offBytes;
        int* cursor     = (int*)p;                  p += curBytes;
        int* bsum       = (int*)p;

        hipMemsetAsync(counts, 0, cntBytes, stream);
        hist_kernel<<<1024, 256, 0, stream>>>(dst, counts, N, E);
        scan1_kernel<<<nb, 256, 0, stream>>>(counts, bsum, N);
        scan2_kernel<<<1, 256, 0, stream>>>(bsum, nb);
        scan3_kernel<<<nb, 256, 0, stream>>>(counts, bsum, offsets8, cursor, N, E);
        fill_kernel<<<1024, 256, 0, stream>>>(src, dst, etype, edge_norm, cursor, packed, N, E);
        agg_kernel<<<2048, 256, 0, stream>>>(packed, offsets8, h, (const float4*)w_comp, G, N);
        transform_kernel<<<1024, 256, 0, stream>>>(G, weight, bias, out, N);
    } else if (ws_size >= gBytes) {
        float* Hb = (float*)d_ws;
        hipMemsetAsync(d_out, 0, (size_t)N * 64 * sizeof(float), stream);
        hb_kernel<<<1024, 256, 0, stream>>>(h, weight, Hb, N);
        edge_kernel<<<2048, 256, 0, stream>>>(Hb, w_comp, edge_norm, src, dst, etype, out, E);
        bias_relu_kernel<<<2048, 256, 0, stream>>>(out, bias, N * 64);
    }
}

// Round 7
// 148.643 us; speedup vs baseline: 1.9937x; 1.3146x over previous
//
#include <hip/hip_runtime.h>

// RGCN layer, basis decomposition — CSR-reordered formulation.
//
//   G[n][b][i] = sum_{e: dst[e]==n} (norm_e * w_comp[etype_e][b]) * h[src_e][i]
//   out[n][o]  = relu( sum_b sum_i G[n][b][i] * weight[b][i][o] + bias[o] )
//
// CSR build is an LDS-privatized counting sort with ZERO global atomics:
//   hist2: per-(chunk,range) block LDS histogram -> plain stores to counts[c][n]
//   scan:  hierarchical exclusive scan; counts[c][n] overwritten in place with
//          per-(chunk,node) start offsets
//   fill2: per-(chunk,range) block re-reads its chunk; position from LDS
//          cursor atomicAdd (block-private, ~20cy) -> scatter packed record
// Then: agg (no atomics, scalarized record loads) -> dense transform GEMM.
//
// Workspace overlay: counts (6.4MB) is dead before G (51.2MB) is born, so G
// overlaps it. Total need ~64MB.

constexpr int NCHUNK = 32;   // edge chunks (counting-sort stability groups)
constexpr int NRANGE = 4;    // node ranges (LDS bins = ceil(N/NRANGE))
constexpr int MAXBIN = 12800; // 51.2KB LDS; requires N <= NRANGE*MAXBIN

// ============================ hist (no global atomics) ============================

__global__ __launch_bounds__(256) void hist2_kernel(const int* __restrict__ dst,
                                                    int* __restrict__ counts,
                                                    int N, int E, int CH, int RS) {
    __shared__ int bins[MAXBIN];
    const int c = blockIdx.x / NRANGE;
    const int r = blockIdx.x % NRANGE;
    const int lo = r * RS;
    const int hi = (lo + RS < N) ? (lo + RS) : N;
    const int nbin = hi - lo;
    for (int i = threadIdx.x; i < nbin; i += 256) bins[i] = 0;
    __syncthreads();

    const int e0 = c * CH;
    const int e1 = (e0 + CH < E) ? (e0 + CH) : E;
    if (e0 < E) {
        const int cnt = e1 - e0;
        const int nq = cnt >> 2;
        const int4* d4p = (const int4*)(dst + e0);
        for (int q = threadIdx.x; q < nq; q += 256) {
            int4 d4 = d4p[q];
            if (d4.x >= lo && d4.x < hi) atomicAdd(&bins[d4.x - lo], 1);
            if (d4.y >= lo && d4.y < hi) atomicAdd(&bins[d4.y - lo], 1);
            if (d4.z >= lo && d4.z < hi) atomicAdd(&bins[d4.z - lo], 1);
            if (d4.w >= lo && d4.w < hi) atomicAdd(&bins[d4.w - lo], 1);
        }
        int rem = cnt & 3;
        if ((int)threadIdx.x < rem) {
            int d = dst[e0 + (nq << 2) + threadIdx.x];
            if (d >= lo && d < hi) atomicAdd(&bins[d - lo], 1);
        }
    }
    __syncthreads();
    int* crow = counts + (size_t)c * N + lo;
    for (int i = threadIdx.x; i < nbin; i += 256) crow[i] = bins[i];
}

// ============================ hierarchical scan ============================

// per-node totals (sum over chunks) -> per-block sums
__global__ __launch_bounds__(256) void scan1_kernel(const int* __restrict__ counts,
                                                    int* __restrict__ bsum, int N) {
    __shared__ int s[256];
    int t = threadIdx.x;
    int n = blockIdx.x * 256 + t;
    int sum = 0;
    if (n < N) {
#pragma unroll
        for (int c = 0; c < NCHUNK; ++c) sum += counts[(size_t)c * N + n];
    }
    s[t] = sum;
    __syncthreads();
    for (int off = 128; off > 0; off >>= 1) {
        if (t < off) s[t] += s[t + off];
        __syncthreads();
    }
    if (t == 0) bsum[blockIdx.x] = s[0];
}

// exclusive scan of block sums (nb <= 256)
__global__ __launch_bounds__(256) void scan2_kernel(int* __restrict__ bsum, int nb) {
    __shared__ int s[256];
    int t = threadIdx.x;
    int v = (t < nb) ? bsum[t] : 0;
    s[t] = v;
    __syncthreads();
    for (int off = 1; off < 256; off <<= 1) {
        int x = (t >= off) ? s[t - off] : 0;
        __syncthreads();
        s[t] += x;
        __syncthreads();
    }
    if (t < nb) bsum[t] = s[t] - v;   // exclusive
}

// per-node base + in-place rewrite counts[c][n] -> per-(chunk,node) start offset
__global__ __launch_bounds__(256) void scan3_kernel(int* __restrict__ counts,
                                                    const int* __restrict__ bsum,
                                                    int* __restrict__ offsets,
                                                    int N, int E) {
    __shared__ int s[256];
    int t = threadIdx.x;
    int n = blockIdx.x * 256 + t;
    int cc[NCHUNK];
    int sum = 0;
    if (n < N) {
#pragma unroll
        for (int c = 0; c < NCHUNK; ++c) {
            cc[c] = counts[(size_t)c * N + n];
            sum += cc[c];
        }
    }
    s[t] = sum;
    __syncthreads();
    for (int off = 1; off < 256; off <<= 1) {
        int x = (t >= off) ? s[t - off] : 0;
        __syncthreads();
        s[t] += x;
        __syncthreads();
    }
    if (n < N) {
        int run = s[t] - sum + bsum[blockIdx.x];
        offsets[n] = run;
#pragma unroll
        for (int c = 0; c < NCHUNK; ++c) {
            counts[(size_t)c * N + n] = run;   // start offset for (chunk c, node n)
            run += cc[c];
        }
    }
    if (blockIdx.x == 0 && t == 0) offsets[N] = E;
}

// ============================ fill (LDS cursors, no global atomics) ============================

__global__ __launch_bounds__(256) void fill2_kernel(const int* __restrict__ src,
                                                    const int* __restrict__ dst,
                                                    const int* __restrict__ etype,
                                                    const float* __restrict__ norm,
                                                    const int* __restrict__ offs,  // counts rewritten
                                                    uint4* __restrict__ packed,
                                                    int N, int E, int CH, int RS) {
    __shared__ int cur[MAXBIN];
    const int c = blockIdx.x / NRANGE;
    const int r = blockIdx.x % NRANGE;
    const int lo = r * RS;
    const int hi = (lo + RS < N) ? (lo + RS) : N;
    const int nbin = hi - lo;
    const int* orow = offs + (size_t)c * N + lo;
    for (int i = threadIdx.x; i < nbin; i += 256) cur[i] = orow[i];
    __syncthreads();

    const int e0 = c * CH;
    const int e1 = (e0 + CH < E) ? (e0 + CH) : E;
    if (e0 >= E) return;
    const int cnt = e1 - e0;
    const int nq = cnt >> 2;
    const int4* d4p = (const int4*)(dst + e0);
    const int4* s4p = (const int4*)(src + e0);
    const int4* t4p = (const int4*)(etype + e0);
    const float4* n4p = (const float4*)(norm + e0);
    for (int q = threadIdx.x; q < nq; q += 256) {
        int4 d4 = d4p[q];
        int4 s4 = s4p[q];
        int4 t4 = t4p[q];
        float4 n4 = n4p[q];
        if (d4.x >= lo && d4.x < hi) {
            int pos = atomicAdd(&cur[d4.x - lo], 1);
            uint4 rec; rec.x = (unsigned)s4.x; rec.y = (unsigned)t4.x;
            rec.z = __float_as_uint(n4.x); rec.w = 0u;
            packed[pos] = rec;
        }
        if (d4.y >= lo && d4.y < hi) {
            int pos = atomicAdd(&cur[d4.y - lo], 1);
            uint4 rec; rec.x = (unsigned)s4.y; rec.y = (unsigned)t4.y;
            rec.z = __float_as_uint(n4.y); rec.w = 0u;
            packed[pos] = rec;
        }
        if (d4.z >= lo && d4.z < hi) {
            int pos = atomicAdd(&cur[d4.z - lo], 1);
            uint4 rec; rec.x = (unsigned)s4.z; rec.y = (unsigned)t4.z;
            rec.z = __float_as_uint(n4.z); rec.w = 0u;
            packed[pos] = rec;
        }
        if (d4.w >= lo && d4.w < hi) {
            int pos = atomicAdd(&cur[d4.w - lo], 1);
            uint4 rec; rec.x = (unsigned)s4.w; rec.y = (unsigned)t4.w;
            rec.z = __float_as_uint(n4.w); rec.w = 0u;
            packed[pos] = rec;
        }
    }
    int rem = cnt & 3;
    if ((int)threadIdx.x < rem) {
        int i = e0 + (nq << 2) + threadIdx.x;
        int d = dst[i];
        if (d >= lo && d < hi) {
            int pos = atomicAdd(&cur[d - lo], 1);
            uint4 rec; rec.x = (unsigned)src[i]; rec.y = (unsigned)etype[i];
            rec.z = __float_as_uint(norm[i]); rec.w = 0u;
            packed[pos] = rec;
        }
    }
}

// ============================ Aggregation ============================
// One wave per node (lane = feature i). Wave index forced uniform via
// readfirstlane so record/coeff loads scalarize; 8-deep phase-separated
// load groups with sched_barrier fences for memory-level parallelism.
__global__ __launch_bounds__(256) void agg_kernel(const uint4* __restrict__ packed,
                                                  const int* __restrict__ offsets,
                                                  const float* __restrict__ h,
                                                  const float4* __restrict__ wc4,
                                                  float* __restrict__ G, int N) {
    const int t = threadIdx.x;
    const int lane = t & 63;
    const int wave = __builtin_amdgcn_readfirstlane((blockIdx.x * blockDim.x + t) >> 6);
    const int nw = (gridDim.x * blockDim.x) >> 6;

    for (int n = wave; n < N; n += nw) {
        const int e0 = offsets[n];
        const int e1 = offsets[n + 1];
        float g0 = 0.f, g1 = 0.f, g2 = 0.f, g3 = 0.f;
        int e = e0;
        for (; e + 8 <= e1; e += 8) {
            uint4 r[8];
#pragma unroll
            for (int k = 0; k < 8; ++k) r[k] = packed[e + k];
            __builtin_amdgcn_sched_barrier(0);
            float hv[8];
            float4 c[8];
#pragma unroll
            for (int k = 0; k < 8; ++k) {
                hv[k] = h[(size_t)r[k].x * 64 + lane];
                c[k] = wc4[r[k].y];
            }
            __builtin_amdgcn_sched_barrier(0);
#pragma unroll
            for (int k = 0; k < 8; ++k) {
                float a = __uint_as_float(r[k].z) * hv[k];
                g0 = fmaf(c[k].x, a, g0);
                g1 = fmaf(c[k].y, a, g1);
                g2 = fmaf(c[k].z, a, g2);
                g3 = fmaf(c[k].w, a, g3);
            }
        }
        if (e + 4 <= e1) {
            uint4 r[4];
#pragma unroll
            for (int k = 0; k < 4; ++k) r[k] = packed[e + k];
            __builtin_amdgcn_sched_barrier(0);
            float hv[4];
            float4 c[4];
#pragma unroll
            for (int k = 0; k < 4; ++k) {
                hv[k] = h[(size_t)r[k].x * 64 + lane];
                c[k] = wc4[r[k].y];
            }
            __builtin_amdgcn_sched_barrier(0);
#pragma unroll
            for (int k = 0; k < 4; ++k) {
                float a = __uint_as_float(r[k].z) * hv[k];
                g0 = fmaf(c[k].x, a, g0);
                g1 = fmaf(c[k].y, a, g1);
                g2 = fmaf(c[k].z, a, g2);
                g3 = fmaf(c[k].w, a, g3);
            }
            e += 4;
        }
        for (; e < e1; ++e) {
            uint4 rec = packed[e];
            float hv = h[(size_t)rec.x * 64 + lane];
            float4 cc = wc4[rec.y];
            float a = __uint_as_float(rec.z) * hv;
            g0 = fmaf(cc.x, a, g0);
            g1 = fmaf(cc.y, a, g1);
            g2 = fmaf(cc.z, a, g2);
            g3 = fmaf(cc.w, a, g3);
        }
        float* gp = G + (size_t)n * 256;
        gp[lane] = g0;
        gp[64 + lane] = g1;
        gp[128 + lane] = g2;
        gp[192 + lane] = g3;
    }
}

// ============================ Transform GEMM ============================
// out[n][o] = relu(bias[o] + sum_b sum_i G[n][b][i]*weight[b][i][o])
__global__ __launch_bounds__(256) void transform_kernel(const float* __restrict__ G,
                                                        const float* __restrict__ weight,
                                                        const float* __restrict__ bias,
                                                        float* __restrict__ out, int N) {
    __shared__ float sh[16 * 256];
    __shared__ float sp[16 * 256];
    const int t = threadIdx.x;
    const int b = t >> 6, o = t & 63;

    float wcol[64];
#pragma unroll
    for (int i = 0; i < 64; ++i) wcol[i] = weight[b * 4096 + i * 64 + o];
    const float bo = bias[o];

    const int ntiles = (N + 15) / 16;
    for (int tile = blockIdx.x; tile < ntiles; tile += gridDim.x) {
        const int n0 = tile * 16;
#pragma unroll
        for (int p = 0; p < 4; ++p) {                   // load 16x256 floats as float4
            int idx = p * 256 + t;
            int row = idx >> 6, col = idx & 63;
            int n = n0 + row;
            float4 v = (n < N) ? ((const float4*)G)[(size_t)n * 64 + col]
                               : make_float4(0.f, 0.f, 0.f, 0.f);
            ((float4*)sh)[idx] = v;
        }
        __syncthreads();
        for (int r = 0; r < 16; ++r) {
            const float* g = &sh[r * 256 + b * 64];     // wave-uniform -> broadcast
            float acc = 0.f;
#pragma unroll
            for (int i = 0; i < 64; i += 4) {
                float4 gv = *(const float4*)&g[i];
                acc = fmaf(gv.x, wcol[i], acc);
                acc = fmaf(gv.y, wcol[i + 1], acc);
                acc = fmaf(gv.z, wcol[i + 2], acc);
                acc = fmaf(gv.w, wcol[i + 3], acc);
            }
            sp[r * 256 + b * 64 + o] = acc;
        }
        __syncthreads();
#pragma unroll
        for (int p = 0; p < 4; ++p) {                   // reduce 4 basis partials
            int j = p * 256 + t;
            int r = j >> 6, oo = j & 63;
            int n = n0 + r;
            if (n < N) {
                float v = sp[r * 256 + oo] + sp[r * 256 + 64 + oo] +
                          sp[r * 256 + 128 + oo] + sp[r * 256 + 192 + oo] + bo;
                out[(size_t)n * 64 + oo] = v > 0.f ? v : 0.f;
            }
        }
        __syncthreads();
    }
}

// ============================ Fallback path ============================

__global__ __launch_bounds__(256) void hb_kernel(const float* __restrict__ h,
                                                 const float* __restrict__ weight,
                                                 float* __restrict__ Hb, int N) {
    __shared__ float sh[16][64];
    const int t = threadIdx.x;
    const int b = t >> 6;
    const int o = t & 63;
    float wcol[64];
#pragma unroll
    for (int i = 0; i < 64; ++i) wcol[i] = weight[b * 4096 + i * 64 + o];
    for (int node0 = blockIdx.x * 16; node0 < N; node0 += gridDim.x * 16) {
        __syncthreads();
#pragma unroll
        for (int p = 0; p < 4; ++p) {
            int idx = p * 256 + t;
            int r = idx >> 6, c = idx & 63;
            int node = node0 + r;
            sh[r][c] = (node < N) ? h[(size_t)node * 64 + c] : 0.f;
        }
        __syncthreads();
        int rmax = (N - node0 < 16) ? (N - node0) : 16;
        for (int r = 0; r < rmax; ++r) {
            float acc = 0.f;
#pragma unroll
            for (int i = 0; i < 64; ++i) acc += sh[r][i] * wcol[i];
            Hb[(size_t)(node0 + r) * 256 + t] = acc;
        }
    }
}

__global__ __launch_bounds__(256) void edge_kernel(const float* __restrict__ Hb,
                                                   const float* __restrict__ w_comp,
                                                   const float* __restrict__ edge_norm,
                                                   const int* __restrict__ src,
                                                   const int* __restrict__ dst,
                                                   const int* __restrict__ etype,
                                                   float* __restrict__ out, int E) {
    const int lane = threadIdx.x & 63;
    const int gwave = (blockIdx.x * blockDim.x + threadIdx.x) >> 6;
    const int nwaves = (gridDim.x * blockDim.x) >> 6;
    const int chunk = (E + nwaves - 1) / nwaves;
    const int e0 = gwave * chunk;
    const int e1 = (e0 + chunk < E) ? (e0 + chunk) : E;
    for (int e = e0; e < e1; ++e) {
        int s = src[e];
        int d = dst[e];
        int r = etype[e];
        float nm = edge_norm[e];
        const float* hb = Hb + (size_t)s * 256;
        const float* cf = w_comp + r * 4;
        float v = cf[0] * hb[lane] + cf[1] * hb[64 + lane] + cf[2] * hb[128 + lane] +
                  cf[3] * hb[192 + lane];
        atomicAdd(&out[(size_t)d * 64 + lane], v * nm);
    }
}

__global__ __launch_bounds__(256) void bias_relu_kernel(float* __restrict__ out,
                                                        const float* __restrict__ bias,
                                                        int total) {
    int i = blockIdx.x * blockDim.x + threadIdx.x;
    int stride = gridDim.x * blockDim.x;
    for (; i < total; i += stride) {
        float v = out[i] + bias[i & 63];
        out[i] = v > 0.f ? v : 0.f;
    }
}

// ============================ Launch ============================

extern "C" void kernel_launch(void* const* d_in, const int* in_sizes, int n_in,
                              void* d_out, int out_size, void* d_ws, size_t ws_size,
                              hipStream_t stream) {
    const float* h         = (const float*)d_in[0];
    const float* weight    = (const float*)d_in[1];
    const float* w_comp    = (const float*)d_in[2];
    const float* bias      = (const float*)d_in[3];
    const float* edge_norm = (const float*)d_in[4];
    const int*   src       = (const int*)d_in[5];
    const int*   dst       = (const int*)d_in[6];
    const int*   etype     = (const int*)d_in[7];
    float* out = (float*)d_out;

    const int N = in_sizes[0] / 64;
    const int E = in_sizes[4];
    const int nb = (N + 255) / 256;
    const int CH = (((E + NCHUNK - 1) / NCHUNK) + 3) & ~3;   // chunk size, x4 aligned
    const int RS = (N + NRANGE - 1) / NRANGE;                // bins per range

    // workspace overlay:
    //   [0, gBytes)                      : counts (NCHUNK*N ints, dead after fill) then G
    //   [gBytes, +packedBytes)           : packed records
    //   [gBytes+packedBytes, ...)        : offsets (N+1), bsum (nb)
    size_t gBytes      = (size_t)N * 256 * sizeof(float);
    size_t cntBytes    = (size_t)NCHUNK * N * sizeof(int);
    size_t packedBytes = (size_t)E * 16;
    size_t tailBytes   = (size_t)(N + 1 + nb + 16) * sizeof(int);
    size_t need        = gBytes + packedBytes + tailBytes;

    if (ws_size >= need && nb <= 256 && RS <= MAXBIN && cntBytes <= gBytes) {
        char* p = (char*)d_ws;
        float* G      = (float*)p;                      // overlays counts
        int* counts   = (int*)p;
        uint4* packed = (uint4*)(p + gBytes);
        int* offsets  = (int*)(p + gBytes + packedBytes);
        int* bsum     = offsets + (N + 1);

        hist2_kernel<<<NCHUNK * NRANGE, 256, 0, stream>>>(dst, counts, N, E, CH, RS);
        scan1_kernel<<<nb, 256, 0, stream>>>(counts, bsum, N);
        scan2_kernel<<<1, 256, 0, stream>>>(bsum, nb);
        scan3_kernel<<<nb, 256, 0, stream>>>(counts, bsum, offsets, N, E);
        fill2_kernel<<<NCHUNK * NRANGE, 256, 0, stream>>>(src, dst, etype, edge_norm,
                                                          counts, packed, N, E, CH, RS);
        agg_kernel<<<2048, 256, 0, stream>>>(packed, offsets, h, (const float4*)w_comp, G, N);
        transform_kernel<<<1024, 256, 0, stream>>>(G, weight, bias, out, N);
    } else if (ws_size >= gBytes) {
        float* Hb = (float*)d_ws;
        hipMemsetAsync(d_out, 0, (size_t)N * 64 * sizeof(float), stream);
        hb_kernel<<<1024, 256, 0, stream>>>(h, weight, Hb, N);
        edge_kernel<<<2048, 256, 0, stream>>>(Hb, w_comp, edge_norm, src, dst, etype, out, E);
        bias_relu_kernel<<<2048, 256, 0, stream>>>(out, bias, N * 64);
    }
}